// Round 8
// baseline (1225.578 us; speedup 1.0000x reference)
//
#include <hip/hip_runtime.h>

#define N_NODES 100000
#define IN_C    128
#define HID_C   64
#define OUT_C   40
#define N_EDGES 1600000

// dst-bucketing: 128 nodes per bucket
#define BSH    7
#define BUCK_N 128
#define NBUCK  ((N_NODES + BUCK_N - 1) >> BSH)           // 782
#define PART_CHUNK 4096
#define NPB    ((N_EDGES + PART_CHUNK - 1) / PART_CHUNK) // 391
#define EPT    (PART_CHUNK / 256)

typedef _Float16 half_t;
typedef _Float16 half8 __attribute__((ext_vector_type(8)));
typedef float    f32x4 __attribute__((ext_vector_type(4)));
typedef unsigned long long ull;

// ---------------------------------------------------------------------------
// init: zero bucket counts + transpose W1 -> W1T [64][128] fp16
// ---------------------------------------------------------------------------
__global__ void k_init(const float* __restrict__ W1, half_t* __restrict__ W1T,
                       int* __restrict__ bcnt) {
    int t = threadIdx.x;  // 1024
    if (t < NBUCK) bcnt[t] = 0;
    for (int i = t; i < IN_C * HID_C; i += 1024) {
        int k = i >> 6, n = i & 63;
        W1T[n * IN_C + k] = (half_t)W1[i];
    }
}

__global__ void k_hist(const int* __restrict__ dst, int* __restrict__ bcnt) {
    __shared__ int lh[NBUCK];
    int tid = threadIdx.x;
    for (int i = tid; i < NBUCK; i += 256) lh[i] = 0;
    __syncthreads();
    int base = blockIdx.x * PART_CHUNK;
#pragma unroll
    for (int j = 0; j < EPT; ++j) {
        int e = base + j * 256 + tid;
        if (e < N_EDGES) atomicAdd(&lh[dst[e] >> BSH], 1);
    }
    __syncthreads();
    for (int i = tid; i < NBUCK; i += 256)
        if (lh[i]) atomicAdd(&bcnt[i], lh[i]);
}

__global__ void k_bscan(const int* __restrict__ bcnt, int* __restrict__ bstart,
                        int* __restrict__ gcur) {
    __shared__ int s[1024];
    int tid = threadIdx.x;  // 1024
    int v = (tid < NBUCK) ? bcnt[tid] : 0;
    s[tid] = v;
    __syncthreads();
    for (int off = 1; off < 1024; off <<= 1) {
        int t = (tid >= off) ? s[tid - off] : 0;
        __syncthreads();
        s[tid] += t;
        __syncthreads();
    }
    if (tid < NBUCK) {
        int excl = s[tid] - v;
        bstart[tid] = excl;
        gcur[tid]   = excl;
    }
    if (tid == 0) bstart[NBUCK] = N_EDGES;
}

// partition edges into bucket order; pairs[pos] = (dst<<32)|src
__global__ void k_part(const int* __restrict__ src, const int* __restrict__ dst,
                       int* __restrict__ gcur, ull* __restrict__ pairs) {
    __shared__ int lh[NBUCK];
    int tid = threadIdx.x;
    for (int i = tid; i < NBUCK; i += 256) lh[i] = 0;
    __syncthreads();
    int base = blockIdx.x * PART_CHUNK;
    int sv[EPT], dv[EPT], rv[EPT];
#pragma unroll
    for (int j = 0; j < EPT; ++j) {
        int e = base + j * 256 + tid;
        if (e < N_EDGES) {
            sv[j] = src[e];
            dv[j] = dst[e];
            rv[j] = atomicAdd(&lh[dv[j] >> BSH], 1);
        } else {
            dv[j] = -1;
        }
    }
    __syncthreads();
    for (int i = tid; i < NBUCK; i += 256) {
        int c = lh[i];
        if (c) lh[i] = atomicAdd(&gcur[i], c);
    }
    __syncthreads();
#pragma unroll
    for (int j = 0; j < EPT; ++j) {
        if (dv[j] >= 0) {
            int pos = lh[dv[j] >> BSH] + rv[j];
            pairs[pos] = ((ull)(unsigned)dv[j] << 32) | (unsigned)sv[j];
        }
    }
}

// per-bucket degree count -> dinv = rsqrt(1 + deg)
__global__ void k_bdeg(const ull* __restrict__ pairs, const int* __restrict__ bstart,
                       float* __restrict__ dinv) {
    __shared__ int lc[BUCK_N];
    int b = blockIdx.x, tid = threadIdx.x;
    if (tid < BUCK_N) lc[tid] = 0;
    __syncthreads();
    int s0 = bstart[b], s1 = bstart[b + 1];
    int nbase = b << BSH;
    for (int e = s0 + tid; e < s1; e += 256)
        atomicAdd(&lc[(int)(pairs[e] >> 32) - nbase], 1);
    __syncthreads();
    int node = nbase + tid;
    if (tid < BUCK_N && node < N_NODES)
        dinv[node] = rsqrtf(1.0f + (float)lc[tid]);
}

// ---------------------------------------------------------------------------
// MFMA GEMM1 + int8 quantization:
//   v[n,c] = dinv[n] * (x[n,:] @ W1)[c];  per-row scale; g1q int8[64]
// ---------------------------------------------------------------------------
__global__ void k_gemm1_mfma(const float* __restrict__ x, const half_t* __restrict__ W1T,
                             const float* __restrict__ dinv, signed char* __restrict__ g1q,
                             float* __restrict__ scales) {
    __shared__ __align__(16) signed char lq[16 * HID_C];
    int lane = threadIdx.x & 63;
    int l16  = lane & 15;
    int lg   = lane >> 4;

    half8 bf[4][4];
#pragma unroll
    for (int ct = 0; ct < 4; ++ct)
#pragma unroll
        for (int kc = 0; kc < 4; ++kc)
            bf[ct][kc] = *(const half8*)(W1T + (ct * 16 + l16) * IN_C + kc * 32 + lg * 8);

#pragma unroll
    for (int s = 0; s < 2; ++s) {
        int r0 = (blockIdx.x * 2 + s) * 16;
        f32x4 acc0 = {0.f, 0.f, 0.f, 0.f};
        f32x4 acc1 = {0.f, 0.f, 0.f, 0.f};
        f32x4 acc2 = {0.f, 0.f, 0.f, 0.f};
        f32x4 acc3 = {0.f, 0.f, 0.f, 0.f};
#pragma unroll
        for (int kc = 0; kc < 4; ++kc) {
            const float* ap = x + (size_t)(r0 + l16) * IN_C + kc * 32 + lg * 8;
            float4 a0 = *(const float4*)ap;
            float4 a1 = *(const float4*)(ap + 4);
            half8 af;
            af[0] = (_Float16)a0.x; af[1] = (_Float16)a0.y;
            af[2] = (_Float16)a0.z; af[3] = (_Float16)a0.w;
            af[4] = (_Float16)a1.x; af[5] = (_Float16)a1.y;
            af[6] = (_Float16)a1.z; af[7] = (_Float16)a1.w;
            acc0 = __builtin_amdgcn_mfma_f32_16x16x32_f16(af, bf[0][kc], acc0, 0, 0, 0);
            acc1 = __builtin_amdgcn_mfma_f32_16x16x32_f16(af, bf[1][kc], acc1, 0, 0, 0);
            acc2 = __builtin_amdgcn_mfma_f32_16x16x32_f16(af, bf[2][kc], acc2, 0, 0, 0);
            acc3 = __builtin_amdgcn_mfma_f32_16x16x32_f16(af, bf[3][kc], acc3, 0, 0, 0);
        }
#pragma unroll
        for (int j = 0; j < 4; ++j) {
            int   r  = r0 + lg * 4 + j;
            float dv = dinv[r];
            float v0 = acc0[j] * dv;
            float v1 = acc1[j] * dv;
            float v2 = acc2[j] * dv;
            float v3 = acc3[j] * dv;
            float m = fmaxf(fmaxf(fabsf(v0), fabsf(v1)), fmaxf(fabsf(v2), fabsf(v3)));
            m = fmaxf(m, __shfl_xor(m, 1));
            m = fmaxf(m, __shfl_xor(m, 2));
            m = fmaxf(m, __shfl_xor(m, 4));
            m = fmaxf(m, __shfl_xor(m, 8));
            float inv = (m > 0.0f) ? 127.0f / m : 0.0f;
            if (l16 == 0) scales[r] = m * (1.0f / 127.0f);
            int q0 = min(127, max(-127, __float2int_rn(v0 * inv)));
            int q1 = min(127, max(-127, __float2int_rn(v1 * inv)));
            int q2 = min(127, max(-127, __float2int_rn(v2 * inv)));
            int q3 = min(127, max(-127, __float2int_rn(v3 * inv)));
            int rl = lg * 4 + j;
            lq[rl * HID_C +  0 + l16] = (signed char)q0;
            lq[rl * HID_C + 16 + l16] = (signed char)q1;
            lq[rl * HID_C + 32 + l16] = (signed char)q2;
            lq[rl * HID_C + 48 + l16] = (signed char)q3;
        }
        uint4 wv = *(const uint4*)(lq + lane * 16);
        *(uint4*)(g1q + (size_t)r0 * HID_C + lane * 16) = wv;
    }
}

// ---------------------------------------------------------------------------
// pull1 stream: one block per dst-bucket. LDS fp32 acc[128][65].
// Edge loop: 4 slots x 16 lanes; slot s handles edge base+j*4+s; pair read is
// slot-broadcast (8B), gather = int8 row (uint/lane), ds_add_f32 accumulate.
// Finalize: hidden = relu(b1 + dinv*acc); g2 = dinv*(hidden@W2); int8-quant.
// ---------------------------------------------------------------------------
__global__ void k_pull1s(const ull* __restrict__ pairs, const int* __restrict__ bstart,
                         const float* __restrict__ dinv, const unsigned* __restrict__ g1v,
                         const float* __restrict__ scales, const float* __restrict__ b1,
                         const float* __restrict__ W2, signed char* __restrict__ g2q,
                         float* __restrict__ scales2) {
    __shared__ float acc[BUCK_N][65];
    __shared__ float w2s[HID_C * OUT_C];
    int tid   = threadIdx.x;
    int b     = blockIdx.x;
    int nbase = b << BSH;

    // init acc with own dequantized rows (self-loop term), zeros for OOB
    for (int idx = tid; idx < BUCK_N * 16; idx += 256) {
        int r  = idx >> 4;
        int c4 = idx & 15;
        int node = nbase + r;
        float vx = 0.f, vy = 0.f, vz = 0.f, vw = 0.f;
        if (node < N_NODES) {
            unsigned u = g1v[(size_t)node * 16 + c4];
            float sc = scales[node];
            char4 c = __builtin_bit_cast(char4, u);
            vx = sc * (float)c.x; vy = sc * (float)c.y;
            vz = sc * (float)c.z; vw = sc * (float)c.w;
        }
        acc[r][c4 * 4 + 0] = vx;
        acc[r][c4 * 4 + 1] = vy;
        acc[r][c4 * 4 + 2] = vz;
        acc[r][c4 * 4 + 3] = vw;
    }
    for (int i = tid; i < HID_C * OUT_C; i += 256) w2s[i] = W2[i];
    __syncthreads();

    int s0 = bstart[b], s1 = bstart[b + 1];
    int lane = tid & 63, wv = tid >> 6;
    int slot = lane >> 4, c4 = lane & 15;

    for (int base = s0 + wv * 16; base < s1; base += 64) {
#pragma unroll
        for (int j = 0; j < 4; ++j) {
            int  eidx = base + j * 4 + slot;
            bool ok   = eidx < s1;
            ull  p    = pairs[ok ? eidx : s0];      // safe in-bucket read
            int  srcj = (int)(unsigned)(p & 0xffffffffu);
            int  drow = (int)(p >> 32) - nbase;
            float sc  = ok ? scales[srcj] : 0.f;
            unsigned u = g1v[(size_t)srcj * 16 + c4];
            char4 c = __builtin_bit_cast(char4, u);
            float* ap = &acc[drow][c4 * 4];
            atomicAdd(ap + 0, sc * (float)c.x);
            atomicAdd(ap + 1, sc * (float)c.y);
            atomicAdd(ap + 2, sc * (float)c.z);
            atomicAdd(ap + 3, sc * (float)c.w);
        }
    }
    __syncthreads();

    // finalize: thread t (0..127) + partner t+128 split k-range
    int t    = tid & 127;
    int half = tid >> 7;
    int node = nbase + t;
    float dn = (node < N_NODES) ? dinv[node] : 0.f;
    float oacc[OUT_C];
#pragma unroll
    for (int j = 0; j < OUT_C; ++j) oacc[j] = 0.f;
    int k0 = half * 32;
    for (int k = k0; k < k0 + 32; ++k) {
        float hv = fmaxf(dn * acc[t][k] + b1[k], 0.f);
        const float* wr = &w2s[k * OUT_C];
#pragma unroll
        for (int j = 0; j < OUT_C; ++j) oacc[j] += hv * wr[j];
    }
    __syncthreads();
    if (half == 1) {
#pragma unroll
        for (int j = 0; j < OUT_C; ++j) acc[t][j] = oacc[j];
    }
    __syncthreads();
    if (half == 0 && node < N_NODES) {
        float m = 0.f;
#pragma unroll
        for (int j = 0; j < OUT_C; ++j) {
            oacc[j] = dn * (oacc[j] + acc[t][j]);
            m = fmaxf(m, fabsf(oacc[j]));
        }
        float inv = (m > 0.f) ? 127.f / m : 0.f;
        scales2[node] = m * (1.f / 127.f);
        unsigned* dstp = (unsigned*)(g2q + (size_t)node * 40);
#pragma unroll
        for (int q = 0; q < 10; ++q) {
            int q0 = min(127, max(-127, __float2int_rn(oacc[q * 4 + 0] * inv)));
            int q1 = min(127, max(-127, __float2int_rn(oacc[q * 4 + 1] * inv)));
            int q2 = min(127, max(-127, __float2int_rn(oacc[q * 4 + 2] * inv)));
            int q3 = min(127, max(-127, __float2int_rn(oacc[q * 4 + 3] * inv)));
            dstp[q] = (unsigned)(q0 & 0xff) | ((unsigned)(q1 & 0xff) << 8) |
                      ((unsigned)(q2 & 0xff) << 16) | ((unsigned)(q3 & 0xff) << 24);
        }
    }
}

// ---------------------------------------------------------------------------
// pull2 stream: g2q rows = 40B int8 (L2-resident, 4MB). 6 slots x 10 lanes.
// out = b2 + dinv*(self + sum_src), self folded into acc init.
// ---------------------------------------------------------------------------
__global__ void k_pull2s(const ull* __restrict__ pairs, const int* __restrict__ bstart,
                         const float* __restrict__ dinv, const unsigned* __restrict__ g2v,
                         const float* __restrict__ scales2, const float* __restrict__ b2,
                         float* __restrict__ out) {
    __shared__ float acc[BUCK_N][41];
    int tid   = threadIdx.x;
    int b     = blockIdx.x;
    int nbase = b << BSH;

    for (int idx = tid; idx < BUCK_N * 10; idx += 256) {
        int r  = idx / 10;
        int c4 = idx - r * 10;
        int node = nbase + r;
        float vx = 0.f, vy = 0.f, vz = 0.f, vw = 0.f;
        if (node < N_NODES) {
            unsigned u = g2v[(size_t)node * 10 + c4];
            float sc = scales2[node];
            char4 c = __builtin_bit_cast(char4, u);
            vx = sc * (float)c.x; vy = sc * (float)c.y;
            vz = sc * (float)c.z; vw = sc * (float)c.w;
        }
        acc[r][c4 * 4 + 0] = vx;
        acc[r][c4 * 4 + 1] = vy;
        acc[r][c4 * 4 + 2] = vz;
        acc[r][c4 * 4 + 3] = vw;
    }
    __syncthreads();

    int s0 = bstart[b], s1 = bstart[b + 1];
    int lane = tid & 63, wv = tid >> 6;
    int slot = lane / 10;                 // 0..5 active, 6 = lanes 60..63 idle
    int c4   = lane - slot * 10;          // 0..9
    bool active = slot < 6;
    int slotc = active ? slot : 5;

    for (int base = s0 + wv * 12; base < s1; base += 48) {
#pragma unroll
        for (int j = 0; j < 2; ++j) {
            int  eidx = base + j * 6 + slotc;
            bool ok   = active && eidx < s1;
            ull  p    = pairs[ok ? eidx : s0];
            int  srcj = (int)(unsigned)(p & 0xffffffffu);
            int  drow = (int)(p >> 32) - nbase;
            float sc  = ok ? scales2[srcj] : 0.f;
            unsigned u = g2v[(size_t)srcj * 10 + c4];
            char4 c = __builtin_bit_cast(char4, u);
            float* ap = &acc[drow][c4 * 4];
            atomicAdd(ap + 0, sc * (float)c.x);
            atomicAdd(ap + 1, sc * (float)c.y);
            atomicAdd(ap + 2, sc * (float)c.z);
            atomicAdd(ap + 3, sc * (float)c.w);
        }
    }
    __syncthreads();

    if (tid < BUCK_N) {
        int node = nbase + tid;
        if (node < N_NODES) {
            float dn = dinv[node];
            float4* op = (float4*)(out + (size_t)node * OUT_C);
#pragma unroll
            for (int q = 0; q < 10; ++q) {
                int j = q * 4;
                float4 r;
                r.x = b2[j + 0] + dn * acc[tid][j + 0];
                r.y = b2[j + 1] + dn * acc[tid][j + 1];
                r.z = b2[j + 2] + dn * acc[tid][j + 2];
                r.w = b2[j + 3] + dn * acc[tid][j + 3];
                op[q] = r;
            }
        }
    }
}

// ---------------------------------------------------------------------------
// launch
// ---------------------------------------------------------------------------
extern "C" void kernel_launch(void* const* d_in, const int* in_sizes, int n_in,
                              void* d_out, int out_size, void* d_ws, size_t ws_size,
                              hipStream_t stream) {
    const float* x   = (const float*)d_in[0];
    const int*   ei  = (const int*)d_in[1];
    const int*   src = ei;
    const int*   dst = ei + N_EDGES;
    const float* W1  = (const float*)d_in[2];
    const float* b1  = (const float*)d_in[3];
    const float* W2  = (const float*)d_in[4];
    const float* b2  = (const float*)d_in[5];
    float*       out = (float*)d_out;

    // workspace (~25 MB)
    int*    bcnt    = (int*)d_ws;                     // NBUCK
    int*    bstart  = bcnt + NBUCK;                   // NBUCK+1
    int*    gcur    = bstart + NBUCK + 1;             // NBUCK
    half_t* w1t     = (half_t*)(gcur + NBUCK);        // 8192 halfs
    float*  dinv    = (float*)(w1t + IN_C * HID_C);   // N
    float*  scales  = dinv + N_NODES;                 // N
    float*  scales2 = scales + N_NODES;               // N
    int*    after   = (int*)(scales2 + N_NODES);
    ull* pairs = (ull*)(((uintptr_t)after + 15) & ~(uintptr_t)15);   // E*8B
    signed char* g1q = (signed char*)(pairs + N_EDGES);              // N*64B
    signed char* g2q = g1q + (size_t)N_NODES * 64;                   // N*40B

    k_init<<<1, 1024, 0, stream>>>(W1, w1t, bcnt);
    k_hist<<<NPB, 256, 0, stream>>>(dst, bcnt);
    k_bscan<<<1, 1024, 0, stream>>>(bcnt, bstart, gcur);
    k_part<<<NPB, 256, 0, stream>>>(src, dst, gcur, pairs);
    k_bdeg<<<NBUCK, 256, 0, stream>>>(pairs, bstart, dinv);

    k_gemm1_mfma<<<N_NODES / 32, 64, 0, stream>>>(x, w1t, dinv, g1q, scales);

    k_pull1s<<<NBUCK, 256, 0, stream>>>(pairs, bstart, dinv, (const unsigned*)g1q,
                                        scales, b1, W2, g2q, scales2);
    k_pull2s<<<NBUCK, 256, 0, stream>>>(pairs, bstart, dinv, (const unsigned*)g2q,
                                        scales2, b2, out);
}

// Round 9
// 201.718 us; speedup vs baseline: 6.0757x; 6.0757x over previous
//
#include <hip/hip_runtime.h>

#define N_NODES 100000
#define IN_C    128
#define HID_C   64
#define OUT_C   40
#define N_EDGES 1600000

// bucketed CSR build (R7 structure)
#define BSH        8
#define NBUCK      ((N_NODES + 255) >> BSH)              // 391 buckets of 256 nodes
#define PART_CHUNK 4096
#define NPB        ((N_EDGES + PART_CHUNK - 1) / PART_CHUNK)  // 391
#define EPT        (PART_CHUNK / 256)

// node-count scan
#define SCAN_ITEMS 1024
#define NB ((N_NODES + SCAN_ITEMS - 1) / SCAN_ITEMS)     // 98

typedef _Float16 half_t;
typedef _Float16 half8   __attribute__((ext_vector_type(8)));
typedef _Float16 half2_t __attribute__((ext_vector_type(2)));
typedef float    f32x4   __attribute__((ext_vector_type(4)));
typedef unsigned long long ull;

// dequant-accumulate 4 int8 channels with row scale
static __device__ __forceinline__ void acc_q(float4& a, unsigned v, float sc, bool ok) {
    char4 c = __builtin_bit_cast(char4, v);
    if (ok) {
        a.x += sc * (float)c.x;
        a.y += sc * (float)c.y;
        a.z += sc * (float)c.z;
        a.w += sc * (float)c.w;
    }
}

// ---------------------------------------------------------------------------
// init: zero bucket counts + W1 -> W1T [64][128] fp16 + W2 -> W2T [48][64] fp16 (pad 0)
// ---------------------------------------------------------------------------
__global__ void k_init(const float* __restrict__ W1, const float* __restrict__ W2,
                       half_t* __restrict__ W1T, half_t* __restrict__ W2T,
                       int* __restrict__ bcnt) {
    int t = threadIdx.x;  // 512
    if (t < NBUCK) bcnt[t] = 0;
    for (int i = t; i < IN_C * HID_C; i += 512) {
        int k = i >> 6, n = i & 63;
        W1T[n * IN_C + k] = (half_t)W1[i];
    }
    for (int i = t; i < 48 * HID_C; i += 512) {
        int n = i >> 6, k = i & 63;
        W2T[n * HID_C + k] = (n < OUT_C) ? (half_t)W2[k * OUT_C + n] : (half_t)0.0f;
    }
}

__global__ void k_hist(const int* __restrict__ dst, int* __restrict__ bcnt) {
    __shared__ int lh[NBUCK];
    int tid = threadIdx.x;
    for (int i = tid; i < NBUCK; i += 256) lh[i] = 0;
    __syncthreads();
    int base = blockIdx.x * PART_CHUNK;
#pragma unroll
    for (int j = 0; j < EPT; ++j) {
        int e = base + j * 256 + tid;
        if (e < N_EDGES) atomicAdd(&lh[dst[e] >> BSH], 1);
    }
    __syncthreads();
    for (int i = tid; i < NBUCK; i += 256)
        if (lh[i]) atomicAdd(&bcnt[i], lh[i]);
}

__global__ void k_bscan(const int* __restrict__ bcnt, int* __restrict__ bstart,
                        int* __restrict__ gcur) {
    __shared__ int s[512];
    int tid = threadIdx.x;
    int v = (tid < NBUCK) ? bcnt[tid] : 0;
    s[tid] = v;
    __syncthreads();
    for (int off = 1; off < 512; off <<= 1) {
        int t = (tid >= off) ? s[tid - off] : 0;
        __syncthreads();
        s[tid] += t;
        __syncthreads();
    }
    if (tid < NBUCK) {
        int excl = s[tid] - v;
        bstart[tid] = excl;
        gcur[tid]   = excl;
    }
    if (tid == 0) bstart[NBUCK] = N_EDGES;
}

__global__ void k_part(const int* __restrict__ src, const int* __restrict__ dst,
                       int* __restrict__ gcur, ull* __restrict__ pairs) {
    __shared__ int lh[NBUCK];
    int tid = threadIdx.x;
    for (int i = tid; i < NBUCK; i += 256) lh[i] = 0;
    __syncthreads();
    int base = blockIdx.x * PART_CHUNK;
    int sv[EPT], dv[EPT], rv[EPT];
#pragma unroll
    for (int j = 0; j < EPT; ++j) {
        int e = base + j * 256 + tid;
        if (e < N_EDGES) {
            sv[j] = src[e];
            dv[j] = dst[e];
            rv[j] = atomicAdd(&lh[dv[j] >> BSH], 1);
        } else {
            dv[j] = -1;
        }
    }
    __syncthreads();
    for (int i = tid; i < NBUCK; i += 256) {
        int c = lh[i];
        if (c) lh[i] = atomicAdd(&gcur[i], c);
    }
    __syncthreads();
#pragma unroll
    for (int j = 0; j < EPT; ++j) {
        if (dv[j] >= 0) {
            int pos = lh[dv[j] >> BSH] + rv[j];
            pairs[pos] = ((ull)(unsigned)dv[j] << 32) | (unsigned)sv[j];
        }
    }
}

__global__ void k_bcount(const ull* __restrict__ pairs,
                         const int* __restrict__ bstart, int* __restrict__ cnt) {
    __shared__ int lc[256];
    int b = blockIdx.x, tid = threadIdx.x;
    lc[tid] = 0;
    __syncthreads();
    int s0 = bstart[b], s1 = bstart[b + 1];
    int nbase = b << BSH;
    for (int e = s0 + tid; e < s1; e += 256)
        atomicAdd(&lc[(int)(pairs[e] >> 32) - nbase], 1);
    __syncthreads();
    int node = nbase + tid;
    if (node < N_NODES) cnt[node] = lc[tid];
}

__global__ void k_scan_blk(const int* __restrict__ cnt, int* __restrict__ cursor,
                           int* __restrict__ blks) {
    __shared__ int s[256];
    int tid = threadIdx.x;
    int base = blockIdx.x * SCAN_ITEMS + tid * 4;
    int a0 = (base + 0 < N_NODES) ? cnt[base + 0] : 0;
    int a1 = (base + 1 < N_NODES) ? cnt[base + 1] : 0;
    int a2 = (base + 2 < N_NODES) ? cnt[base + 2] : 0;
    int a3 = (base + 3 < N_NODES) ? cnt[base + 3] : 0;
    int tsum = a0 + a1 + a2 + a3;
    s[tid] = tsum;
    __syncthreads();
    for (int off = 1; off < 256; off <<= 1) {
        int t = (tid >= off) ? s[tid - off] : 0;
        __syncthreads();
        s[tid] += t;
        __syncthreads();
    }
    int texcl = s[tid] - tsum;
    if (base + 0 < N_NODES) cursor[base + 0] = texcl;
    if (base + 1 < N_NODES) cursor[base + 1] = texcl + a0;
    if (base + 2 < N_NODES) cursor[base + 2] = texcl + a0 + a1;
    if (base + 3 < N_NODES) cursor[base + 3] = texcl + a0 + a1 + a2;
    if (tid == 0) blks[blockIdx.x] = s[255];
}

__global__ void k_scan_top(int* __restrict__ blks) {
    __shared__ int s[128];
    int tid = threadIdx.x;
    int v = (tid < NB) ? blks[tid] : 0;
    s[tid] = v;
    __syncthreads();
    for (int off = 1; off < 128; off <<= 1) {
        int t = (tid >= off) ? s[tid - off] : 0;
        __syncthreads();
        s[tid] += t;
        __syncthreads();
    }
    if (tid < NB) blks[tid] = s[tid] - v;
}

__global__ void k_scan_add(const int* __restrict__ cnt, int* __restrict__ cursor,
                           const int* __restrict__ blks, float* __restrict__ dinv) {
    int tid = threadIdx.x;
    int base = blockIdx.x * SCAN_ITEMS + tid * 4;
    int off = blks[blockIdx.x];
#pragma unroll
    for (int j = 0; j < 4; ++j) {
        int i = base + j;
        if (i < N_NODES) {
            cursor[i] += off;
            dinv[i] = rsqrtf(1.0f + (float)cnt[i]);
        }
    }
}

__global__ void k_bfill(const ull* __restrict__ pairs,
                        const int* __restrict__ bstart, const int* __restrict__ cursor,
                        int* __restrict__ esrc) {
    __shared__ int lcur[256];
    int b = blockIdx.x, tid = threadIdx.x;
    int nbase = b << BSH;
    int node = nbase + tid;
    lcur[tid] = (node < N_NODES) ? cursor[node] : 0;
    __syncthreads();
    int s0 = bstart[b], s1 = bstart[b + 1];
    for (int e = s0 + tid; e < s1; e += 256) {
        ull p = pairs[e];
        int d = (int)(p >> 32);
        int s = (int)(p & 0xffffffffu);
        int pos = atomicAdd(&lcur[d - nbase], 1);
        esrc[pos] = s;
    }
}

// ---------------------------------------------------------------------------
// MFMA GEMM1 + int8 quantization (unchanged from R7)
// ---------------------------------------------------------------------------
__global__ void k_gemm1_mfma(const float* __restrict__ x, const half_t* __restrict__ W1T,
                             const float* __restrict__ dinv, signed char* __restrict__ g1q,
                             float* __restrict__ scales) {
    __shared__ __align__(16) signed char lq[16 * HID_C];
    int lane = threadIdx.x & 63;
    int l16  = lane & 15;
    int lg   = lane >> 4;

    half8 bf[4][4];
#pragma unroll
    for (int ct = 0; ct < 4; ++ct)
#pragma unroll
        for (int kc = 0; kc < 4; ++kc)
            bf[ct][kc] = *(const half8*)(W1T + (ct * 16 + l16) * IN_C + kc * 32 + lg * 8);

#pragma unroll
    for (int s = 0; s < 2; ++s) {
        int r0 = (blockIdx.x * 2 + s) * 16;
        f32x4 acc0 = {0.f, 0.f, 0.f, 0.f};
        f32x4 acc1 = {0.f, 0.f, 0.f, 0.f};
        f32x4 acc2 = {0.f, 0.f, 0.f, 0.f};
        f32x4 acc3 = {0.f, 0.f, 0.f, 0.f};
#pragma unroll
        for (int kc = 0; kc < 4; ++kc) {
            const float* ap = x + (size_t)(r0 + l16) * IN_C + kc * 32 + lg * 8;
            float4 a0 = *(const float4*)ap;
            float4 a1 = *(const float4*)(ap + 4);
            half8 af;
            af[0] = (_Float16)a0.x; af[1] = (_Float16)a0.y;
            af[2] = (_Float16)a0.z; af[3] = (_Float16)a0.w;
            af[4] = (_Float16)a1.x; af[5] = (_Float16)a1.y;
            af[6] = (_Float16)a1.z; af[7] = (_Float16)a1.w;
            acc0 = __builtin_amdgcn_mfma_f32_16x16x32_f16(af, bf[0][kc], acc0, 0, 0, 0);
            acc1 = __builtin_amdgcn_mfma_f32_16x16x32_f16(af, bf[1][kc], acc1, 0, 0, 0);
            acc2 = __builtin_amdgcn_mfma_f32_16x16x32_f16(af, bf[2][kc], acc2, 0, 0, 0);
            acc3 = __builtin_amdgcn_mfma_f32_16x16x32_f16(af, bf[3][kc], acc3, 0, 0, 0);
        }
#pragma unroll
        for (int j = 0; j < 4; ++j) {
            int   r  = r0 + lg * 4 + j;
            float dv = dinv[r];
            float v0 = acc0[j] * dv;
            float v1 = acc1[j] * dv;
            float v2 = acc2[j] * dv;
            float v3 = acc3[j] * dv;
            float m = fmaxf(fmaxf(fabsf(v0), fabsf(v1)), fmaxf(fabsf(v2), fabsf(v3)));
            m = fmaxf(m, __shfl_xor(m, 1));
            m = fmaxf(m, __shfl_xor(m, 2));
            m = fmaxf(m, __shfl_xor(m, 4));
            m = fmaxf(m, __shfl_xor(m, 8));
            float inv = (m > 0.0f) ? 127.0f / m : 0.0f;
            if (l16 == 0) scales[r] = m * (1.0f / 127.0f);
            int q0 = min(127, max(-127, __float2int_rn(v0 * inv)));
            int q1 = min(127, max(-127, __float2int_rn(v1 * inv)));
            int q2 = min(127, max(-127, __float2int_rn(v2 * inv)));
            int q3 = min(127, max(-127, __float2int_rn(v3 * inv)));
            int rl = lg * 4 + j;
            lq[rl * HID_C +  0 + l16] = (signed char)q0;
            lq[rl * HID_C + 16 + l16] = (signed char)q1;
            lq[rl * HID_C + 32 + l16] = (signed char)q2;
            lq[rl * HID_C + 48 + l16] = (signed char)q3;
        }
        uint4 wv = *(const uint4*)(lq + lane * 16);
        *(uint4*)(g1q + (size_t)r0 * HID_C + lane * 16) = wv;
    }
}

// ---------------------------------------------------------------------------
// pull layer1: gather+accumulate only (R7 loop); epilogue = bias+relu ->
// h1 fp16 row store (128B coalesced). No LDS, no W2 loop.
// ---------------------------------------------------------------------------
__global__ void k_pull1(const int* __restrict__ cursor, const int* __restrict__ cnt,
                        const int* __restrict__ esrc, const float* __restrict__ dinv,
                        const unsigned* __restrict__ g1v, const float* __restrict__ scales,
                        const float* __restrict__ b1, half_t* __restrict__ h1) {
    int w    = threadIdx.x >> 6;
    int lane = threadIdx.x & 63;
    int n    = blockIdx.x * 4 + w;
    int h    = lane >> 4;    // slot 0..3
    int c4   = lane & 15;    // channel quad

    float dn  = dinv[n];
    int start = cursor[n];
    int end   = start + cnt[n];

    float4 acc = {0.f, 0.f, 0.f, 0.f};
    if (h == 0)
        acc_q(acc, g1v[(size_t)n * 16 + c4], scales[n], true);  // self row

    int e = start;
    for (; e + 8 <= end; e += 8) {
        int i0 = esrc[e + h];
        int i1 = esrc[e + h + 4];
        unsigned v0 = g1v[(size_t)i0 * 16 + c4];
        float    s0 = scales[i0];
        unsigned v1 = g1v[(size_t)i1 * 16 + c4];
        float    s1 = scales[i1];
        acc_q(acc, v0, s0, true);
        acc_q(acc, v1, s1, true);
    }
    for (; e < end; e += 4) {
        int  ee  = e + h;
        bool ok  = ee < end;
        int  idx = esrc[ok ? ee : end - 1];
        unsigned v = g1v[(size_t)idx * 16 + c4];
        float    s = scales[idx];
        acc_q(acc, v, s, ok);
    }

    // butterfly over slot bits
    acc.x += __shfl_xor(acc.x, 16); acc.y += __shfl_xor(acc.y, 16);
    acc.z += __shfl_xor(acc.z, 16); acc.w += __shfl_xor(acc.w, 16);
    acc.x += __shfl_xor(acc.x, 32); acc.y += __shfl_xor(acc.y, 32);
    acc.z += __shfl_xor(acc.z, 32); acc.w += __shfl_xor(acc.w, 32);

    if (h == 0) {
        float4 bb = ((const float4*)b1)[c4];
        float rx = fmaxf(dn * acc.x + bb.x, 0.0f);
        float ry = fmaxf(dn * acc.y + bb.y, 0.0f);
        float rz = fmaxf(dn * acc.z + bb.z, 0.0f);
        float rw = fmaxf(dn * acc.w + bb.w, 0.0f);
        half2_t p0; p0.x = (_Float16)rx; p0.y = (_Float16)ry;
        half2_t p1; p1.x = (_Float16)rz; p1.y = (_Float16)rw;
        uint2 u;
        u.x = __builtin_bit_cast(unsigned, p0);
        u.y = __builtin_bit_cast(unsigned, p1);
        *(uint2*)(h1 + (size_t)n * HID_C + c4 * 4) = u;
    }
}

// ---------------------------------------------------------------------------
// MFMA GEMM2: g2 = dinv * (h1 @ W2), int8 row-quantized (40B rows) + scales2.
// W2T padded to 48 cols (zeros). Mirrors gemm1 structure.
// ---------------------------------------------------------------------------
__global__ void k_gemm2_mfma(const half_t* __restrict__ h1, const half_t* __restrict__ W2T,
                             const float* __restrict__ dinv, signed char* __restrict__ g2q,
                             float* __restrict__ scales2) {
    __shared__ __align__(16) signed char lq[16 * 40];
    int lane = threadIdx.x & 63;
    int l16  = lane & 15;
    int lg   = lane >> 4;

    half8 bf[3][2];
#pragma unroll
    for (int ct = 0; ct < 3; ++ct)
#pragma unroll
        for (int kc = 0; kc < 2; ++kc)
            bf[ct][kc] = *(const half8*)(W2T + (ct * 16 + l16) * HID_C + kc * 32 + lg * 8);

#pragma unroll
    for (int s = 0; s < 2; ++s) {
        int r0 = (blockIdx.x * 2 + s) * 16;
        f32x4 acc0 = {0.f, 0.f, 0.f, 0.f};
        f32x4 acc1 = {0.f, 0.f, 0.f, 0.f};
        f32x4 acc2 = {0.f, 0.f, 0.f, 0.f};
#pragma unroll
        for (int kc = 0; kc < 2; ++kc) {
            half8 af = *(const half8*)(h1 + (size_t)(r0 + l16) * HID_C + kc * 32 + lg * 8);
            acc0 = __builtin_amdgcn_mfma_f32_16x16x32_f16(af, bf[0][kc], acc0, 0, 0, 0);
            acc1 = __builtin_amdgcn_mfma_f32_16x16x32_f16(af, bf[1][kc], acc1, 0, 0, 0);
            acc2 = __builtin_amdgcn_mfma_f32_16x16x32_f16(af, bf[2][kc], acc2, 0, 0, 0);
        }
#pragma unroll
        for (int j = 0; j < 4; ++j) {
            int   r  = r0 + lg * 4 + j;
            float dv = dinv[r];
            float v0 = acc0[j] * dv;
            float v1 = acc1[j] * dv;
            float v2 = (l16 < 8) ? acc2[j] * dv : 0.0f;
            float m = fmaxf(fmaxf(fabsf(v0), fabsf(v1)), fabsf(v2));
            m = fmaxf(m, __shfl_xor(m, 1));
            m = fmaxf(m, __shfl_xor(m, 2));
            m = fmaxf(m, __shfl_xor(m, 4));
            m = fmaxf(m, __shfl_xor(m, 8));
            float inv = (m > 0.0f) ? 127.0f / m : 0.0f;
            if (l16 == 0) scales2[r] = m * (1.0f / 127.0f);
            int q0 = min(127, max(-127, __float2int_rn(v0 * inv)));
            int q1 = min(127, max(-127, __float2int_rn(v1 * inv)));
            int q2 = min(127, max(-127, __float2int_rn(v2 * inv)));
            int rl = lg * 4 + j;
            lq[rl * 40 +  0 + l16] = (signed char)q0;
            lq[rl * 40 + 16 + l16] = (signed char)q1;
            if (l16 < 8) lq[rl * 40 + 32 + l16] = (signed char)q2;
        }
        // 16 rows x 40B = 640B contiguous
        if (lane < 40)
            *(uint4*)(g2q + (size_t)r0 * 40 + lane * 16) = *(const uint4*)(lq + lane * 16);
    }
}

// ---------------------------------------------------------------------------
// pull layer2 -> out. int8 40B rows (g2q ~4MB, L2-resident).
// 4 slots x 16 lanes (10 active per slot); butterfly combine.
// ---------------------------------------------------------------------------
__global__ void k_pull2(const int* __restrict__ cursor, const int* __restrict__ cnt,
                        const int* __restrict__ esrc, const float* __restrict__ dinv,
                        const unsigned* __restrict__ g2v, const float* __restrict__ scales2,
                        const float* __restrict__ b2, float* __restrict__ out) {
    int w    = threadIdx.x >> 6;
    int lane = threadIdx.x & 63;
    int n    = blockIdx.x * 4 + w;
    int h    = lane >> 4;            // slot 0..3
    int c4   = lane & 15;            // 0..15; valid channels at c4<10
    bool cval = c4 < 10;
    int  cc   = cval ? c4 : 9;       // clamped (same row/line, harmless)

    float dn  = dinv[n];
    int start = cursor[n];
    int end   = start + cnt[n];

    float4 acc = {0.f, 0.f, 0.f, 0.f};
    if (h == 0)
        acc_q(acc, g2v[(size_t)n * 10 + cc], cval ? scales2[n] : 0.f, true);  // self

    int e = start;
    for (; e + 8 <= end; e += 8) {
        int i0 = esrc[e + h];
        int i1 = esrc[e + h + 4];
        unsigned v0 = g2v[(size_t)i0 * 10 + cc];
        float    s0 = cval ? scales2[i0] : 0.f;
        unsigned v1 = g2v[(size_t)i1 * 10 + cc];
        float    s1 = cval ? scales2[i1] : 0.f;
        acc_q(acc, v0, s0, true);
        acc_q(acc, v1, s1, true);
    }
    for (; e < end; e += 4) {
        int  ee  = e + h;
        bool ok  = ee < end;
        int  idx = esrc[ok ? ee : end - 1];
        unsigned v = g2v[(size_t)idx * 10 + cc];
        float    s = cval ? scales2[idx] : 0.f;
        acc_q(acc, v, s, ok);
    }

    acc.x += __shfl_xor(acc.x, 16); acc.y += __shfl_xor(acc.y, 16);
    acc.z += __shfl_xor(acc.z, 16); acc.w += __shfl_xor(acc.w, 16);
    acc.x += __shfl_xor(acc.x, 32); acc.y += __shfl_xor(acc.y, 32);
    acc.z += __shfl_xor(acc.z, 32); acc.w += __shfl_xor(acc.w, 32);

    if (h == 0 && cval) {
        float4 bb = ((const float4*)b2)[c4];
        float4 r;
        r.x = bb.x + dn * acc.x;
        r.y = bb.y + dn * acc.y;
        r.z = bb.z + dn * acc.z;
        r.w = bb.w + dn * acc.w;
        ((float4*)(out + (size_t)n * OUT_C))[c4] = r;
    }
}

// ---------------------------------------------------------------------------
// launch
// ---------------------------------------------------------------------------
extern "C" void kernel_launch(void* const* d_in, const int* in_sizes, int n_in,
                              void* d_out, int out_size, void* d_ws, size_t ws_size,
                              hipStream_t stream) {
    const float* x   = (const float*)d_in[0];
    const int*   ei  = (const int*)d_in[1];
    const int*   src = ei;
    const int*   dst = ei + N_EDGES;
    const float* W1  = (const float*)d_in[2];
    const float* b1  = (const float*)d_in[3];
    const float* W2  = (const float*)d_in[4];
    const float* b2  = (const float*)d_in[5];
    float*       out = (float*)d_out;

    // workspace (~45 MB, no overlays; proven ws >= 51.6MB from R1)
    int*    cnt    = (int*)d_ws;                      // N
    int*    cursor = cnt + N_NODES;                   // N
    int*    blks   = cursor + N_NODES;                // 128
    int*    bcnt   = blks + 128;                      // NBUCK
    int*    bstart = bcnt + NBUCK;                    // NBUCK+1
    int*    gcur   = bstart + NBUCK + 1;              // NBUCK
    half_t* w1t    = (half_t*)(gcur + NBUCK);         // 8192 halfs
    half_t* w2t    = w1t + IN_C * HID_C;              // 48*64 halfs
    float*  dinv   = (float*)(w2t + 48 * HID_C);      // N
    float*  scales = dinv + N_NODES;                  // N
    float*  scales2= scales + N_NODES;                // N
    int*    esrc   = (int*)(scales2 + N_NODES);       // E
    int*    after  = esrc + N_EDGES;
    ull*    pairs  = (ull*)(((uintptr_t)after + 15) & ~(uintptr_t)15);  // E*8B
    signed char* g1q = (signed char*)(pairs + N_EDGES);                 // N*64B
    half_t* h1 = (half_t*)(g1q + (size_t)N_NODES * 64);                 // N*64 halfs
    signed char* g2q = (signed char*)(h1 + (size_t)N_NODES * HID_C);    // N*40B

    // CSR build (bucketed, R7)
    k_init<<<1, 512, 0, stream>>>(W1, W2, w1t, w2t, bcnt);
    k_hist<<<NPB, 256, 0, stream>>>(dst, bcnt);
    k_bscan<<<1, 512, 0, stream>>>(bcnt, bstart, gcur);
    k_part<<<NPB, 256, 0, stream>>>(src, dst, gcur, pairs);
    k_bcount<<<NBUCK, 256, 0, stream>>>(pairs, bstart, cnt);
    k_scan_blk<<<NB, 256, 0, stream>>>(cnt, cursor, blks);
    k_scan_top<<<1, 128, 0, stream>>>(blks);
    k_scan_add<<<NB, 256, 0, stream>>>(cnt, cursor, blks, dinv);
    k_bfill<<<NBUCK, 256, 0, stream>>>(pairs, bstart, cursor, esrc);

    // layer 1 transform: g1q = int8(dinv * (x @ W1)), per-row scales
    k_gemm1_mfma<<<N_NODES / 32, 64, 0, stream>>>(x, w1t, dinv, g1q, scales);

    // pull layer 1 -> h1 (fp16 hidden, bias+relu applied)
    k_pull1<<<N_NODES / 4, 256, 0, stream>>>(cursor, cnt, esrc, dinv,
                                             (const unsigned*)g1q, scales, b1, h1);

    // GEMM2 (MFMA): g2q = int8(dinv * (h1 @ W2)) + scales2
    k_gemm2_mfma<<<N_NODES / 32, 64, 0, stream>>>(h1, w2t, dinv, g2q, scales2);

    // pull layer 2 -> out
    k_pull2<<<N_NODES / 4, 256, 0, stream>>>(cursor, cnt, esrc, dinv,
                                             (const unsigned*)g2q, scales2, b2, out);
}